// Round 9
// baseline (385.565 us; speedup 1.0000x reference)
//
#include <hip/hip_runtime.h>
#include <hip/hip_bf16.h>

// ---------------- helpers ----------------
typedef __attribute__((ext_vector_type(8))) short bf16x8;
typedef __attribute__((ext_vector_type(4))) float f32x4;
typedef __attribute__((ext_vector_type(2))) float f32x2;

__device__ __forceinline__ unsigned short f2bf(float f) {
    __hip_bfloat16 h = __float2bfloat16(f);   // round-to-nearest-even
    return __builtin_bit_cast(unsigned short, h);
}
__device__ __forceinline__ unsigned int packbf(float lo, float hi) {
    return (unsigned int)f2bf(lo) | ((unsigned int)f2bf(hi) << 16);
}

// ---------------- fused conversions + histogram (one launch) ----------------
// region 0 (nbq blocks): x fp32 -> offset-u8 (per-row-half fp32 scale), wave/row
// region 1 (nbh blocks): dst histogram + per-edge rank capture
// region 2 (640 blocks): W1/W2/W3 [K][N] fp32 -> [N][K] bf16 transpose
__global__ void k_cvt_hist(const float* __restrict__ x, unsigned char* __restrict__ xq8,
                           float* __restrict__ xsc, int M, int nbq,
                           const int* __restrict__ dst, int* __restrict__ counts,
                           int* __restrict__ rank, int E, int nbh,
                           const float* __restrict__ W1, unsigned short* __restrict__ w1t,
                           const float* __restrict__ W2, unsigned short* __restrict__ w2t,
                           const float* __restrict__ W3, unsigned short* __restrict__ w3t) {
    int b = blockIdx.x;
    if (b < nbq) {
        // x quant: one wave per row; lane covers feats 2l..2l+1; half = lane>>5
        int r = b * 4 + (threadIdx.x >> 6);
        if (r >= M) return;
        int lane = threadIdx.x & 63;
        float2 v = ((const float2*)(x + (size_t)r * 128))[lane];
        float mx = fmaxf(fabsf(v.x), fabsf(v.y));
#pragma unroll
        for (int off = 1; off < 32; off <<= 1) mx = fmaxf(mx, __shfl_xor(mx, off, 64));
        float sc = mx * (1.0f / 127.0f);
        float inv = mx > 0.f ? 127.0f / mx : 0.0f;
        unsigned u0 = (unsigned)fmaf(v.x, inv, 128.5f);   // offset encode
        unsigned u1 = (unsigned)fmaf(v.y, inv, 128.5f);
        ((unsigned short*)(xq8 + (size_t)r * 128))[lane] = (unsigned short)(u0 | (u1 << 8));
        if ((lane & 31) == 0) xsc[r * 2 + (lane >> 5)] = sc;
        return;
    }
    b -= nbq;
    if (b < nbh) {
        int e = b * 256 + threadIdx.x;
        if (e < E) rank[e] = atomicAdd(&counts[dst[e]], 1);
        return;
    }
    b -= nbh;
    const float* w; unsigned short* wt; int K;
    if (b < 128)      { w = W1; wt = w1t; K = 128; }
    else if (b < 384) { w = W2; wt = w2t; K = 256; b -= 128; }
    else              { w = W3; wt = w3t; K = 256; b -= 384; }
    int i = b * 256 + threadIdx.x;   // i < K*256
    int k = i >> 8, n = i & 255;
    wt[n * K + k] = f2bf(w[i]);
}

// ---------------- scan: block offset by re-reduction (no psum kernel) ----------------
__global__ void k_scan_rs(const int* __restrict__ counts, int* __restrict__ row_start,
                          int NN, int E) {
    __shared__ int s[256];
    int t = threadIdx.x;
    int b = blockIdx.x;
    // boff = sum counts[0 .. b*256)
    int lim = b * 256;
    int p = 0;
    for (int i = t; i < lim; i += 256) p += counts[i];
    s[t] = p; __syncthreads();
    for (int off = 128; off > 0; off >>= 1) {
        if (t < off) s[t] += s[t + off];
        __syncthreads();
    }
    int boff = s[0];
    __syncthreads();
    // local exclusive scan of this block's 256 counts
    int i = lim + t;
    int v = (i < NN) ? counts[i] : 0;
    s[t] = v; __syncthreads();
    for (int off = 1; off < 256; off <<= 1) {
        int u = (t >= off) ? s[t - off] : 0;
        __syncthreads();
        s[t] += u;
        __syncthreads();
    }
    int ex = s[t] - v + boff;
    if (i < NN) row_start[i] = ex;
    if (i == NN - 1) row_start[NN] = E;
}

// atomic-free fill; node ids < 65536 so csrc is ushort
__global__ void k_fill(const int* __restrict__ src, const int* __restrict__ dst,
                       const int* __restrict__ rank, const int* __restrict__ row_start,
                       unsigned short* __restrict__ csrc, int E) {
    int e = blockIdx.x * blockDim.x + threadIdx.x;
    if (e < E) csrc[row_start[dst[e]] + rank[e]] = (unsigned short)src[e];
}

// ---------------- layer-1 aggregation: offset-u8 x rows (1 line/row) ----------------
// acc[f] += ubyte*sc with corr += sc per row; final = acc - 128*corr.
__global__ __launch_bounds__(256)
void k_agg8x(const unsigned char* __restrict__ xq8, const float* __restrict__ xsc,
             const int* __restrict__ rs, const unsigned short* __restrict__ csrc,
             unsigned short* __restrict__ out, int NN) {
    int gid = blockIdx.x * blockDim.x + threadIdx.x;
    int node = gid >> 6;
    if (node >= NN) return;
    int lane = threadIdx.x & 63;
    int half = lane >> 5, l32 = lane & 31;
    int hoff = l32 >> 4;               // which 64-feat half this lane's 4 feats sit in
    int k0 = rs[node], k1 = rs[node + 1];
    int cnt = k1 - k0;

    f32x2 acc[4][2];
    float corr[4];
#pragma unroll
    for (int b = 0; b < 4; ++b) {
        acc[b][0] = (f32x2){0.f, 0.f}; acc[b][1] = (f32x2){0.f, 0.f}; corr[b] = 0.f;
    }

    auto accum = [&](int b, unsigned v, float sc) {
        acc[b][0].x += (float)(v & 0xff) * sc;
        acc[b][0].y += (float)((v >> 8) & 0xff) * sc;
        acc[b][1].x += (float)((v >> 16) & 0xff) * sc;
        acc[b][1].y += (float)(v >> 24) * sc;
        corr[b] += sc;
    };

    for (int base = 0; base < cnt; base += 64) {
        int nk = min(cnt - base, 64);
        int myidx = (lane < nk) ? (int)csrc[k0 + base + lane] : 0;
        int j = 0;
        for (; j + 8 <= nk; j += 8) {
            int s[4]; unsigned v[4]; float sc[4];
#pragma unroll
            for (int b = 0; b < 4; ++b) s[b] = __shfl(myidx, j + 2 * b + half, 64);
#pragma unroll
            for (int b = 0; b < 4; ++b) {
                v[b] = ((const unsigned*)(xq8 + (size_t)s[b] * 128))[l32];
                sc[b] = xsc[s[b] * 2 + hoff];
            }
#pragma unroll
            for (int b = 0; b < 4; ++b) accum(b, v[b], sc[b]);
        }
        for (; j < nk; j += 2) {
            int jj = j + half;
            int s = __shfl(myidx, jj < nk ? jj : 0, 64);
            if (jj < nk) {
                unsigned v = ((const unsigned*)(xq8 + (size_t)s * 128))[l32];
                accum(0, v, xsc[s * 2 + hoff]);
            }
        }
    }

#pragma unroll
    for (int i = 0; i < 2; ++i) {
        acc[0][i] += acc[1][i];
        acc[2][i] += acc[3][i];
        acc[0][i] += acc[2][i];
    }
    corr[0] += corr[1]; corr[2] += corr[3]; corr[0] += corr[2];
#pragma unroll
    for (int i = 0; i < 2; ++i) {
        acc[0][i].x += __shfl(acc[0][i].x, l32 + 32, 64);
        acc[0][i].y += __shfl(acc[0][i].y, l32 + 32, 64);
    }
    corr[0] += __shfl(corr[0], l32 + 32, 64);
    if (half == 0) {
        float c128 = 128.0f * corr[0];
        uint2 o;
        o.x = packbf(acc[0][0].x - c128, acc[0][0].y - c128);
        o.y = packbf(acc[0][1].x - c128, acc[0][1].y - c128);
        ((uint2*)(out + (size_t)node * 128))[l32] = o;
    }
}

// ---------------- layers 2&3 aggregation: u8 h rows (2 lines/row) ----------------
__global__ __launch_bounds__(256)
void k_agg8(const unsigned char* __restrict__ h8, const float* __restrict__ scales,
            const int* __restrict__ rs, const unsigned short* __restrict__ csrc,
            unsigned short* __restrict__ out, int NN) {
    int gid = blockIdx.x * blockDim.x + threadIdx.x;
    int node = gid >> 6;
    if (node >= NN) return;
    int lane = threadIdx.x & 63;
    int half = lane >> 5, l32 = lane & 31;
    int qoff = l32 >> 3;               // 64-col quarter of this lane's 8 feats
    int k0 = rs[node], k1 = rs[node + 1];
    int cnt = k1 - k0;

    f32x2 acc[4][4];
#pragma unroll
    for (int b = 0; b < 4; ++b)
#pragma unroll
        for (int i = 0; i < 4; ++i) acc[b][i] = (f32x2){0.f, 0.f};

    auto accum = [&](int b, uint2 v, float sc) {
        unsigned x = v.x, y = v.y;
        acc[b][0].x += (float)(x & 0xff) * sc;
        acc[b][0].y += (float)((x >> 8) & 0xff) * sc;
        acc[b][1].x += (float)((x >> 16) & 0xff) * sc;
        acc[b][1].y += (float)(x >> 24) * sc;
        acc[b][2].x += (float)(y & 0xff) * sc;
        acc[b][2].y += (float)((y >> 8) & 0xff) * sc;
        acc[b][3].x += (float)((y >> 16) & 0xff) * sc;
        acc[b][3].y += (float)(y >> 24) * sc;
    };

    for (int base = 0; base < cnt; base += 64) {
        int nk = min(cnt - base, 64);
        int myidx = (lane < nk) ? (int)csrc[k0 + base + lane] : 0;
        int j = 0;
        for (; j + 8 <= nk; j += 8) {
            int s[4]; uint2 v[4]; float sc[4];
#pragma unroll
            for (int b = 0; b < 4; ++b) s[b] = __shfl(myidx, j + 2 * b + half, 64);
#pragma unroll
            for (int b = 0; b < 4; ++b) {
                v[b] = ((const uint2*)(h8 + (size_t)s[b] * 256))[l32];
                sc[b] = scales[s[b] * 4 + qoff];
            }
#pragma unroll
            for (int b = 0; b < 4; ++b) accum(b, v[b], sc[b]);
        }
        for (; j < nk; j += 2) {
            int jj = j + half;
            int s = __shfl(myidx, jj < nk ? jj : 0, 64);
            if (jj < nk) {
                uint2 v = ((const uint2*)(h8 + (size_t)s * 256))[l32];
                accum(0, v, scales[s * 4 + qoff]);
            }
        }
    }

#pragma unroll
    for (int i = 0; i < 4; ++i) {
        acc[0][i] += acc[1][i];
        acc[2][i] += acc[3][i];
        acc[0][i] += acc[2][i];
    }
#pragma unroll
    for (int i = 0; i < 4; ++i) {
        acc[0][i].x += __shfl(acc[0][i].x, l32 + 32, 64);
        acc[0][i].y += __shfl(acc[0][i].y, l32 + 32, 64);
    }
    if (half == 0) {
        uint4 o;
        o.x = packbf(acc[0][0].x, acc[0][0].y); o.y = packbf(acc[0][1].x, acc[0][1].y);
        o.z = packbf(acc[0][2].x, acc[0][2].y); o.w = packbf(acc[0][3].x, acc[0][3].y);
        ((uint4*)(out + (size_t)node * 256))[l32] = o;
    }
}

// ---------------- MFMA GEMM: C = relu(A @ W + b) ----------------
// QUANT=true: write uint8 h + per-(row, 64-col) fp32 scale. else fp32 out.
#define BM 128
#define BN 128
#define BK 32
#define LDA 40   // padded row stride in shorts (2-way bank alias = free)

template <bool QUANT>
__global__ __launch_bounds__(256)
void k_gemm(const unsigned short* __restrict__ A, const unsigned short* __restrict__ Bt,
            const float* __restrict__ bias, void* __restrict__ Cout,
            float* __restrict__ scales, int M, int K) {
    __shared__ unsigned short As[BM * LDA];
    __shared__ unsigned short Bs[BN * LDA];
    int tid = threadIdx.x;
    int mbase = blockIdx.x * BM;
    int nbase = blockIdx.y * BN;
    int w = tid >> 6, lane = tid & 63, quad = lane >> 4, l16 = lane & 15;
    int wm = w & 1, wn = w >> 1;     // 2x2 wave grid -> 64x64 tile per wave

    f32x4 acc[4][4];
#pragma unroll
    for (int i = 0; i < 4; ++i)
#pragma unroll
        for (int j = 0; j < 4; ++j) acc[i][j] = (f32x4){0.f, 0.f, 0.f, 0.f};

    for (int kk0 = 0; kk0 < K; kk0 += BK) {
        for (int c = tid; c < 512; c += 256) {
            int r = c >> 2, kk = (c & 3) * 8;
            int row = mbase + r; if (row >= M) row = M - 1;   // clamp; tail rows never stored
            uint4 v = *((const uint4*)(A + (size_t)row * K + kk0 + kk));
            *((uint4*)&As[r * LDA + kk]) = v;
        }
        for (int c = tid; c < 512; c += 256) {
            int r = c >> 2, kk = (c & 3) * 8;
            uint4 v = *((const uint4*)(Bt + (size_t)(nbase + r) * K + kk0 + kk));
            *((uint4*)&Bs[r * LDA + kk]) = v;
        }
        __syncthreads();

        bf16x8 af[4], bfr[4];
#pragma unroll
        for (int mt = 0; mt < 4; ++mt) {
            int r = wm * 64 + mt * 16 + l16;
            af[mt] = *((const bf16x8*)&As[r * LDA + quad * 8]);
        }
#pragma unroll
        for (int nt = 0; nt < 4; ++nt) {
            int n = wn * 64 + nt * 16 + l16;
            bfr[nt] = *((const bf16x8*)&Bs[n * LDA + quad * 8]);
        }
#pragma unroll
        for (int mt = 0; mt < 4; ++mt)
#pragma unroll
            for (int nt = 0; nt < 4; ++nt)
                acc[mt][nt] = __builtin_amdgcn_mfma_f32_16x16x32_bf16(af[mt], bfr[nt], acc[mt][nt], 0, 0, 0);
        __syncthreads();
    }

    // bias + relu in-place.  C/D layout: col = lane&15, row = quad*4 + reg
    float bv[4];
#pragma unroll
    for (int nt = 0; nt < 4; ++nt) bv[nt] = bias[nbase + wn * 64 + nt * 16 + l16];
#pragma unroll
    for (int mt = 0; mt < 4; ++mt)
#pragma unroll
        for (int nt = 0; nt < 4; ++nt)
#pragma unroll
            for (int r = 0; r < 4; ++r) {
                float v = acc[mt][nt][r] + bv[nt];
                acc[mt][nt][r] = v > 0.f ? v : 0.f;
            }

    if constexpr (QUANT) {
        unsigned char* h8 = (unsigned char*)Cout;
        int qid = blockIdx.y * 2 + wn;   // 64-col quarter id
#pragma unroll
        for (int mt = 0; mt < 4; ++mt) {
#pragma unroll
            for (int r = 0; r < 4; ++r) {
                float mx = fmaxf(fmaxf(acc[mt][0][r], acc[mt][1][r]),
                                 fmaxf(acc[mt][2][r], acc[mt][3][r]));
#pragma unroll
                for (int off = 1; off < 16; off <<= 1)
                    mx = fmaxf(mx, __shfl_xor(mx, off, 64));
                float inv = mx > 0.f ? 255.0f / mx : 0.0f;
                int m = mbase + wm * 64 + mt * 16 + quad * 4 + r;
                if (m < M) {
#pragma unroll
                    for (int nt = 0; nt < 4; ++nt) {
                        int n = nbase + wn * 64 + nt * 16 + l16;
                        unsigned u = (unsigned)(acc[mt][nt][r] * inv + 0.5f);
                        h8[(size_t)m * 256 + n] = (unsigned char)u;
                    }
                    if (l16 == 0) scales[(size_t)m * 4 + qid] = mx * (1.0f / 255.0f);
                }
            }
        }
    } else {
        float* C = (float*)Cout;
#pragma unroll
        for (int mt = 0; mt < 4; ++mt)
#pragma unroll
            for (int nt = 0; nt < 4; ++nt) {
                int n = nbase + wn * 64 + nt * 16 + l16;
#pragma unroll
                for (int r = 0; r < 4; ++r) {
                    int m = mbase + wm * 64 + mt * 16 + quad * 4 + r;
                    if (m < M) C[(size_t)m * 256 + n] = acc[mt][nt][r];
                }
            }
    }
}

// ---------------- host ----------------
static inline size_t alignup(size_t x) { return (x + 255) & ~(size_t)255; }

extern "C" void kernel_launch(void* const* d_in, const int* in_sizes, int n_in,
                              void* d_out, int out_size, void* d_ws, size_t ws_size,
                              hipStream_t stream) {
    const float* x  = (const float*)d_in[0];
    const int* ei   = (const int*)d_in[1];    // int32 on device (harness converts)
    const float* W1 = (const float*)d_in[2];
    const float* b1 = (const float*)d_in[3];
    const float* W2 = (const float*)d_in[4];
    const float* b2 = (const float*)d_in[5];
    const float* W3 = (const float*)d_in[6];
    const float* b3 = (const float*)d_in[7];

    const int M = in_sizes[0] / 128;      // 50000 nodes
    const int E = in_sizes[1] / 2;        // 800000 edges
    const int* srcp = ei;
    const int* dstp = ei + E;

    // workspace carve-up (~38 MB). h8 (12.8 MB) + scales (0.8 MB) live in
    // d_out: both dead before gemm3 overwrites d_out with fp32.
    char* p = (char*)d_ws;
    size_t off = 0;
    auto carve = [&](size_t bytes) { void* r = p + off; off += alignup(bytes); return r; };
    int* counts    = (int*)carve((size_t)M * 4);
    int* row_start = (int*)carve((size_t)(M + 1) * 4);
    int* rank      = (int*)carve((size_t)E * 4);
    unsigned short* csrc = (unsigned short*)carve((size_t)E * 2);
    unsigned short* w1t = (unsigned short*)carve((size_t)128 * 256 * 2);
    unsigned short* w2t = (unsigned short*)carve((size_t)256 * 256 * 2);
    unsigned short* w3t = (unsigned short*)carve((size_t)256 * 256 * 2);
    unsigned char* xq8  = (unsigned char*)carve((size_t)M * 128);
    float* xsc          = (float*)carve((size_t)M * 2 * 4);
    unsigned short* ab  = (unsigned short*)carve((size_t)M * 256 * 2);  // a1/a2/a3 (bf16)
    unsigned char* h8   = (unsigned char*)d_out;                         // h1/h2 int8
    float* scales       = (float*)((char*)d_out + (size_t)M * 256);      // 4 per node

    const int nbq = (M + 3) / 4;          // x-quant: wave per row, 4 rows/block
    const int nbh = (E + 255) / 256;      // histogram blocks
    const int nscan = (M + 255) / 256;

    // 1) conversions + histogram (fused), then scan, then fill
    hipMemsetAsync(counts, 0, (size_t)M * 4, stream);
    k_cvt_hist<<<nbq + nbh + 640, 256, 0, stream>>>(
        x, xq8, xsc, M, nbq, dstp, counts, rank, E, nbh,
        W1, w1t, W2, w2t, W3, w3t);
    k_scan_rs<<<nscan, 256, 0, stream>>>(counts, row_start, M, E);
    k_fill<<<nbh, 256, 0, stream>>>(srcp, dstp, rank, row_start, csrc, E);

    dim3 ggrid((M + BM - 1) / BM, 2);
    int aggblocks = (M * 64 + 255) / 256;

    // layer 1: a1 = agg8x(x); h1 = quant8(relu(a1 @ W1 + b1))
    k_agg8x<<<aggblocks, 256, 0, stream>>>(xq8, xsc, row_start, csrc, ab, M);
    k_gemm<true><<<ggrid, 256, 0, stream>>>(ab, w1t, b1, h8, scales, M, 128);

    // layer 2: a2 = agg8(h1); h2 = quant8(relu(a2 @ W2 + b2))
    k_agg8<<<aggblocks, 256, 0, stream>>>(h8, scales, row_start, csrc, ab, M);
    k_gemm<true><<<ggrid, 256, 0, stream>>>(ab, w2t, b2, h8, scales, M, 256);

    // layer 3: a3 = agg8(h2); out = relu(a3 @ W3 + b3)
    k_agg8<<<aggblocks, 256, 0, stream>>>(h8, scales, row_start, csrc, ab, M);
    k_gemm<false><<<ggrid, 256, 0, stream>>>(ab, w3t, b3, d_out, nullptr, M, 256);
}